// Round 4
// baseline (322.361 us; speedup 1.0000x reference)
//
#include <hip/hip_runtime.h>
#include <math.h>

#define N_NODES 100000
#define N_EDGES 1600000
#define D_FEAT 32
#define D_HID 64
#define D_OUT 64
#define CAP 48          // per-node slot capacity; deg ~ Poisson(16), P(>48) ~ 1e-12
#define PREP_B 1024     // prep blocks (256 thr): 8192 waves = full residency
#define AGG_B 1024      // agg blocks (256 thr): 4096 waves, ~24 nodes/wave

typedef _Float16 half8 __attribute__((ext_vector_type(8)));
typedef float f32x4  __attribute__((ext_vector_type(4)));

// packed f16 relu(v - q): clang lowers to v_pk_add_f16 + v_pk_max_f16
__device__ inline half8 h8_subrelu(half8 v, half8 q) {
    half8 z = {};
    return __builtin_elementwise_max(v - q, z);
}

// ---------------------------------------------------------------------------
// Kernel 1: fused direct scatter + node precompute.
// Rounds 2/3 lesson: the two-phase coarse binning (~90-100 us) was the long
// pole — 400K global atomics onto a 6 KB counter array (same-line
// serialization), LDS cursor atomics, and partial-line coarse writes. It is
// replaced by a single direct scatter: p = atomicAdd(&cnt[d]); slot[d*CAP+p]
// = s. Atomics spread over 400 KB (6250 lines) pipeline freely; with 8192
// co-resident waves the ~6 dependent atomic rounds per thread cost only a
// few us. slot = 192 B/node = 3 aligned 64B lines.
//
// Phase 2 (same threads, no barrier — outputs independent): node precompute
// (f32 math, f16 store; |v|,|q| <~ 100 so f16 range safe):
//   q[n][k] = pos[n] @ W1[32:35];  v[n][k] = b1[k] + x[n] @ W1[:32] + q[n][k]
// Per-thread sequencing (not block parity) keeps full machine width for each
// phase; atomic-stalled waves overlap other waves' FMA chains.
// ---------------------------------------------------------------------------
__global__ __launch_bounds__(256)
void prep_kernel(const int* __restrict__ src,
                 const int* __restrict__ dst,
                 int* __restrict__ cnt,
                 int* __restrict__ slot,
                 const float* __restrict__ x,
                 const float* __restrict__ pos,
                 const float* __restrict__ W1,
                 const float* __restrict__ b1,
                 unsigned short* __restrict__ vb,
                 unsigned short* __restrict__ qb) {
    const int tid  = blockIdx.x * 256 + threadIdx.x;
    const int nthr = PREP_B * 256;

    // ---- phase 1: edge scatter ----
    for (int e = tid; e < N_EDGES; e += nthr) {
        int d = dst[e], s = src[e];
        int p = atomicAdd(&cnt[d], 1);
        if (p < CAP) slot[(size_t)d * CAP + p] = s;
    }

    // ---- phase 2: node precompute ----
    const int lane = threadIdx.x & 63;
    const int wid  = tid >> 6;
    const int nw   = nthr >> 6;            // 4096 waves

    float w[D_FEAT + 3];
#pragma unroll
    for (int f = 0; f < D_FEAT + 3; ++f)
        w[f] = W1[f * D_HID + lane];
    const float bb = b1[lane];

    for (int node = wid; node < N_NODES; node += nw) {
        const float* xr = x + (size_t)node * D_FEAT;
        float acc = bb;
#pragma unroll
        for (int f = 0; f < D_FEAT; ++f)
            acc = fmaf(xr[f], w[f], acc);

        const float* pr = pos + (size_t)node * 3;
        float qa = 0.0f;
#pragma unroll
        for (int p = 0; p < 3; ++p)
            qa = fmaf(pr[p], w[D_FEAT + p], qa);

        vb[(size_t)node * D_HID + lane] =
            __builtin_bit_cast(unsigned short, (_Float16)(acc + qa));
        qb[(size_t)node * D_HID + lane] =
            __builtin_bit_cast(unsigned short, (_Float16)qa);
    }
}

// ---------------------------------------------------------------------------
// Kernel 2: per-node MFMA aggregation, NO LDS / NO barriers.
// Grid-stride: one node per wave iteration (~24 nodes/wave). Per batch of 16
// rows: slot read is 16 consecutive ints (one 64B line, broadcast across
// quads); A[m][k] = relu(v[src_m][k] - q[i][k]) via packed
// v_pk_add_f16/v_pk_max_f16; layer-2 via 4x2 mfma_f32_16x16x32_f16;
// register max; coalesced store. Padding rows use src = i (self-loop,
// idempotent under max).
// ---------------------------------------------------------------------------
__global__ __launch_bounds__(256)
void agg_kernel(const unsigned short* __restrict__ vb,
                const unsigned short* __restrict__ qb,
                const float* __restrict__ W2,
                const float* __restrict__ b2,
                const int* __restrict__ cnt,
                const int* __restrict__ slot,
                float* __restrict__ out) {
    const int tid   = threadIdx.x;
    const int lane  = tid & 63;
    const int quad  = lane >> 4;
    const int mrow  = lane & 15;
    const int gwave = (blockIdx.x * 256 + tid) >> 6;
    const int nwave = (AGG_B * 256) >> 6;      // 4096

    // B fragments: bfrag[t][kh][j] = W2[kh*32 + quad*8 + j][t*16 + mrow] (f16)
    half8 bfrag[4][2];
#pragma unroll
    for (int t = 0; t < 4; ++t)
#pragma unroll
        for (int kh = 0; kh < 2; ++kh) {
            half8 f;
#pragma unroll
            for (int j = 0; j < 8; ++j)
                f[j] = (_Float16)W2[(kh * 32 + quad * 8 + j) * D_OUT + t * 16 + mrow];
            bfrag[t][kh] = f;
        }
    float bias[4];
#pragma unroll
    for (int t = 0; t < 4; ++t) bias[t] = b2[t * 16 + mrow];

    for (int node = gwave; node < N_NODES; node += nwave) {
        const half8 q0 = *(const half8*)(qb + (size_t)node * D_HID + quad * 8);
        const half8 q1 = *(const half8*)(qb + (size_t)node * D_HID + 32 + quad * 8);

        int deg = cnt[node];
        if (deg > CAP) deg = CAP;
        const int rows = deg + 1;              // + self-loop
        const int nbat = (rows + 15) >> 4;

        float rmax[4][4];
#pragma unroll
        for (int t = 0; t < 4; ++t)
#pragma unroll
            for (int r = 0; r < 4; ++r) rmax[t][r] = -INFINITY;

        const int* srow = slot + (size_t)node * CAP;
        for (int b = 0; b < nbat; ++b) {
            int idx = b * 16 + mrow;
            int idxc = (idx < CAP) ? idx : (CAP - 1);    // clamp slot read
            int s = (idx < deg) ? srow[idxc] : node;

            const half8 v0 = *(const half8*)(vb + (size_t)s * D_HID + quad * 8);
            const half8 v1 = *(const half8*)(vb + (size_t)s * D_HID + 32 + quad * 8);

            half8 a0 = h8_subrelu(v0, q0);
            half8 a1 = h8_subrelu(v1, q1);

#pragma unroll
            for (int t = 0; t < 4; ++t) {
                f32x4 acc = (f32x4){0.f, 0.f, 0.f, 0.f};
                acc = __builtin_amdgcn_mfma_f32_16x16x32_f16(a0, bfrag[t][0], acc, 0, 0, 0);
                acc = __builtin_amdgcn_mfma_f32_16x16x32_f16(a1, bfrag[t][1], acc, 0, 0, 0);
#pragma unroll
                for (int r = 0; r < 4; ++r)
                    rmax[t][r] = fmaxf(rmax[t][r], acc[r]);
            }
        }

        float fin[4];
#pragma unroll
        for (int t = 0; t < 4; ++t) {
            float m = fmaxf(fmaxf(rmax[t][0], rmax[t][1]), fmaxf(rmax[t][2], rmax[t][3]));
            m = fmaxf(m, __shfl_xor(m, 16, 64));
            m = fmaxf(m, __shfl_xor(m, 32, 64));
            fin[t] = m + bias[t];
        }
        float r = (quad == 0) ? fin[0] : (quad == 1) ? fin[1] : (quad == 2) ? fin[2] : fin[3];
        out[(size_t)node * D_OUT + lane] = r;
    }
}

// ---------------------------------------------------------------------------
extern "C" void kernel_launch(void* const* d_in, const int* in_sizes, int n_in,
                              void* d_out, int out_size, void* d_ws, size_t ws_size,
                              hipStream_t stream) {
    const float* x   = (const float*)d_in[0];
    const float* pos = (const float*)d_in[1];
    const int*   ei  = (const int*)d_in[2];   // [2][N_EDGES]: row0=src, row1=dst
    const float* W1  = (const float*)d_in[3];
    const float* b1  = (const float*)d_in[4];
    const float* W2  = (const float*)d_in[5];
    const float* b2  = (const float*)d_in[6];
    float* out = (float*)d_out;

    char* ws = (char*)d_ws;
    unsigned short* vb   = (unsigned short*)ws;                     // 12.8 MB (f16)
    unsigned short* qb   = (unsigned short*)(ws + 12800000);        // 12.8 MB (f16)
    int*            cnt  = (int*)(ws + 25600000);                   // 400 KB
    int*            slot = (int*)(ws + 26000000);                   // 19.2 MB
    // total ws use: 45.2 MB; slot base (26,000,000) is 64B-aligned so each
    // node's 192B slot row = exactly 3 aligned lines.

    const int* src = ei;
    const int* dst = ei + N_EDGES;

    (void)hipMemsetAsync(cnt, 0, N_NODES * sizeof(int), stream);
    hipLaunchKernelGGL(prep_kernel, dim3(PREP_B), dim3(256), 0, stream,
                       src, dst, cnt, slot, x, pos, W1, b1, vb, qb);
    hipLaunchKernelGGL(agg_kernel, dim3(AGG_B), dim3(256), 0, stream,
                       vb, qb, W2, b2, cnt, slot, out);
}

// Round 5
// 222.869 us; speedup vs baseline: 1.4464x; 1.4464x over previous
//
#include <hip/hip_runtime.h>
#include <hip/hip_bf16.h>
#include <math.h>

#define N_NODES 100000
#define N_EDGES 1600000
#define D_FEAT 32
#define D_HID 64
#define D_OUT 64
#define CAP 48          // per-node slot capacity; deg ~ Poisson(16), safe
#define NPB 64          // nodes per coarse bucket (1<<6)
#define NBKT 1563       // ceil(100000/64)
#define ECAP 1536       // edge capacity per coarse bucket (mean 1024, ~16 sigma)
#define B1 256          // binning blocks
#define E_PER_B1 6250   // 256 * 6250 = 1.6M edges exactly
#define NB_NODE 1024    // node-precompute blocks
#define GPAD 16         // gcnt padding: 16 ints = 64B = one line per counter.
                        // R0's gcnt[1563] packed 63 counters/line -> 400K
                        // device-scope far-atomics serialized on 25 lines
                        // (~16K ops/line). One counter per line -> 256
                        // ops/line, parallel across channels.

typedef short bf16x8 __attribute__((ext_vector_type(8)));
typedef float f32x4  __attribute__((ext_vector_type(4)));

__device__ inline unsigned short f2bf(float f) {   // RNE f32 -> bf16
    unsigned u = __float_as_uint(f);
    u += 0x7fff + ((u >> 16) & 1);
    return (unsigned short)(u >> 16);
}
__device__ inline float bf2f(unsigned short h) {
    return __uint_as_float(((unsigned)h) << 16);
}

// ---------------------------------------------------------------------------
// Kernel 1: per-node precompute (f32 math, bf16 store)  [R0-identical]
//   q[n][k] = pos[n] @ W1[32:35];  v[n][k] = b1[k] + x[n] @ W1[:32] + q[n][k]
// per-edge layer-1 output = relu(v[src] - q[dst]).
// ---------------------------------------------------------------------------
__global__ __launch_bounds__(256)
void node_kernel(const float* __restrict__ x,
                 const float* __restrict__ pos,
                 const float* __restrict__ W1,
                 const float* __restrict__ b1,
                 unsigned short* __restrict__ vb,
                 unsigned short* __restrict__ qb) {
    const int lane = threadIdx.x & 63;
    const int wid  = (blockIdx.x * blockDim.x + threadIdx.x) >> 6;
    const int nw   = (NB_NODE * 256) >> 6;

    float w[D_FEAT + 3];
#pragma unroll
    for (int f = 0; f < D_FEAT + 3; ++f)
        w[f] = W1[f * D_HID + lane];
    const float bb = b1[lane];

    for (int node = wid; node < N_NODES; node += nw) {
        const float* xr = x + (size_t)node * D_FEAT;
        float acc = bb;
#pragma unroll
        for (int f = 0; f < D_FEAT; ++f)
            acc = fmaf(xr[f], w[f], acc);

        const float* pr = pos + (size_t)node * 3;
        float qa = 0.0f;
#pragma unroll
        for (int p = 0; p < 3; ++p)
            qa = fmaf(pr[p], w[D_FEAT + p], qa);

        vb[(size_t)node * D_HID + lane] = f2bf(acc + qa);
        qb[(size_t)node * D_HID + lane] = f2bf(qa);
    }
}

// ---------------------------------------------------------------------------
// Kernel 2: two-phase binning [R0-identical except padded gcnt].
// Per block: LDS histogram -> one global atomicAdd per active bucket to
// reserve a contiguous range -> placement via LDS cursors (dense appends).
// Entry packing: (src << 6) | (dst & 63).
// ---------------------------------------------------------------------------
__global__ __launch_bounds__(1024)
void bin_kernel(const int* __restrict__ src,
                const int* __restrict__ dst,
                int* __restrict__ gcnt,
                unsigned int* __restrict__ coarse) {
    __shared__ int hist[NBKT];
    const int tid = threadIdx.x;
    const int e0 = blockIdx.x * E_PER_B1;
    const int e1 = e0 + E_PER_B1;          // 256 * 6250 == N_EDGES exactly

    for (int b = tid; b < NBKT; b += 1024) hist[b] = 0;
    __syncthreads();

    for (int e = e0 + tid; e < e1; e += 1024)
        atomicAdd(&hist[dst[e] >> 6], 1);
    __syncthreads();

    for (int b = tid; b < NBKT; b += 1024) {
        int c = hist[b];
        hist[b] = (c > 0) ? atomicAdd(&gcnt[b * GPAD], c) : 0;
    }
    __syncthreads();

    for (int e = e0 + tid; e < e1; e += 1024) {
        int d = dst[e], s = src[e];
        int b = d >> 6;
        int pos = atomicAdd(&hist[b], 1);
        if (pos < ECAP)
            coarse[(size_t)b * ECAP + pos] = ((unsigned)s << 6) | (unsigned)(d & 63);
    }
}

// ---------------------------------------------------------------------------
// Kernel 3: fused fine-bucketing + per-node MFMA aggregation [R0-identical].
// Block = one coarse bucket, 256 threads = 4 waves. Dense read of the
// bucket's edge list; per-node slot lists in LDS; each wave aggregates 16
// nodes: A[m][k] = relu(v[src_m][k] - q[i][k]), layer-2 via 4x2
// mfma_f32_16x16x32_bf16, register max, coalesced store. Padding rows use
// src = i (self-loop, idempotent under max).
// ---------------------------------------------------------------------------
__global__ __launch_bounds__(256)
void agg_kernel(const unsigned short* __restrict__ vb,
                const unsigned short* __restrict__ qb,
                const float* __restrict__ W2,
                const float* __restrict__ b2,
                const int* __restrict__ gcnt,
                const unsigned int* __restrict__ coarse,
                float* __restrict__ out) {
    __shared__ int lcnt[NPB];
    __shared__ int lslots[NPB][CAP];

    const int tid  = threadIdx.x;
    const int lane = tid & 63;
    const int wave = tid >> 6;             // 0..3
    const int quad = lane >> 4;
    const int mrow = lane & 15;
    const int bkt  = blockIdx.x;
    const int nbase = bkt << 6;

    // B fragments: bfrag[t][kh][j] = W2[kh*32 + quad*8 + j][t*16 + mrow]
    bf16x8 bfrag[4][2];
#pragma unroll
    for (int t = 0; t < 4; ++t)
#pragma unroll
        for (int kh = 0; kh < 2; ++kh) {
            bf16x8 f;
#pragma unroll
            for (int j = 0; j < 8; ++j)
                f[j] = (short)f2bf(W2[(kh * 32 + quad * 8 + j) * D_OUT + t * 16 + mrow]);
            bfrag[t][kh] = f;
        }
    float bias[4];
#pragma unroll
    for (int t = 0; t < 4; ++t) bias[t] = b2[t * 16 + mrow];

    // fine bucketing into LDS
    int E_b = gcnt[bkt * GPAD];
    if (E_b > ECAP) E_b = ECAP;
    for (int i = tid; i < NPB; i += 256) lcnt[i] = 0;
    __syncthreads();
    for (int i = tid; i < E_b; i += 256) {
        unsigned enc = coarse[(size_t)bkt * ECAP + i];
        int local = (int)(enc & 63u);
        int s     = (int)(enc >> 6);
        int p = atomicAdd(&lcnt[local], 1);
        if (p < CAP) lslots[local][p] = s;
    }
    __syncthreads();

    // per-node aggregation, 16 nodes per wave
    for (int ln = wave; ln < NPB; ln += 4) {
        const int node = nbase + ln;
        if (node >= N_NODES) break;

        float qf[2][8];
#pragma unroll
        for (int kh = 0; kh < 2; ++kh) {
            bf16x8 qv = *(const bf16x8*)(qb + (size_t)node * D_HID + kh * 32 + quad * 8);
#pragma unroll
            for (int j = 0; j < 8; ++j) qf[kh][j] = bf2f((unsigned short)qv[j]);
        }

        int deg = lcnt[ln];
        if (deg > CAP) deg = CAP;
        const int rows = deg + 1;              // + self-loop
        const int nbat = (rows + 15) >> 4;

        float rmax[4][4];
#pragma unroll
        for (int t = 0; t < 4; ++t)
#pragma unroll
            for (int r = 0; r < 4; ++r) rmax[t][r] = -INFINITY;

        for (int b = 0; b < nbat; ++b) {
            int idx = b * 16 + mrow;
            int idxc = (idx < CAP) ? idx : (CAP - 1);    // clamp LDS read
            int s = (idx < deg) ? lslots[ln][idxc] : node;

            bf16x8 afrag[2];
#pragma unroll
            for (int kh = 0; kh < 2; ++kh) {
                bf16x8 vv = *(const bf16x8*)(vb + (size_t)s * D_HID + kh * 32 + quad * 8);
                bf16x8 a;
#pragma unroll
                for (int j = 0; j < 8; j += 2) {
                    float h0 = fmaxf(bf2f((unsigned short)vv[j])     - qf[kh][j],     0.0f);
                    float h1 = fmaxf(bf2f((unsigned short)vv[j + 1]) - qf[kh][j + 1], 0.0f);
                    __hip_bfloat162 p2 = __float22bfloat162_rn(make_float2(h0, h1));
                    a[j]     = (short)__bfloat16_as_ushort(p2.x);
                    a[j + 1] = (short)__bfloat16_as_ushort(p2.y);
                }
                afrag[kh] = a;
            }

            f32x4 acc[4];
#pragma unroll
            for (int t = 0; t < 4; ++t) {
                acc[t] = (f32x4){0.f, 0.f, 0.f, 0.f};
                acc[t] = __builtin_amdgcn_mfma_f32_16x16x32_bf16(afrag[0], bfrag[t][0], acc[t], 0, 0, 0);
                acc[t] = __builtin_amdgcn_mfma_f32_16x16x32_bf16(afrag[1], bfrag[t][1], acc[t], 0, 0, 0);
#pragma unroll
                for (int r = 0; r < 4; ++r)
                    rmax[t][r] = fmaxf(rmax[t][r], acc[t][r]);
            }
        }

        float fin[4];
#pragma unroll
        for (int t = 0; t < 4; ++t) {
            float m = fmaxf(fmaxf(rmax[t][0], rmax[t][1]), fmaxf(rmax[t][2], rmax[t][3]));
            m = fmaxf(m, __shfl_xor(m, 16, 64));
            m = fmaxf(m, __shfl_xor(m, 32, 64));
            fin[t] = m + bias[t];
        }
        float r = (quad == 0) ? fin[0] : (quad == 1) ? fin[1] : (quad == 2) ? fin[2] : fin[3];
        out[(size_t)node * D_OUT + lane] = r;
    }
}

// ---------------------------------------------------------------------------
extern "C" void kernel_launch(void* const* d_in, const int* in_sizes, int n_in,
                              void* d_out, int out_size, void* d_ws, size_t ws_size,
                              hipStream_t stream) {
    const float* x   = (const float*)d_in[0];
    const float* pos = (const float*)d_in[1];
    const int*   ei  = (const int*)d_in[2];   // [2][N_EDGES]: row0=src, row1=dst
    const float* W1  = (const float*)d_in[3];
    const float* b1  = (const float*)d_in[4];
    const float* W2  = (const float*)d_in[5];
    const float* b2  = (const float*)d_in[6];
    float* out = (float*)d_out;

    char* ws = (char*)d_ws;
    unsigned short* vb   = (unsigned short*)ws;                     // 12.8 MB
    unsigned short* qb   = (unsigned short*)(ws + 12800000);        // 12.8 MB
    int*            gcnt = (int*)(ws + 25600000);                   // 100 KB (padded)
    unsigned int* coarse = (unsigned int*)(ws + 25700096);          // 9.6 MB

    const int* src = ei;
    const int* dst = ei + N_EDGES;

    (void)hipMemsetAsync(gcnt, 0, NBKT * GPAD * sizeof(int), stream);
    hipLaunchKernelGGL(bin_kernel, dim3(B1), dim3(1024), 0, stream,
                       src, dst, gcnt, coarse);
    hipLaunchKernelGGL(node_kernel, dim3(NB_NODE), dim3(256), 0, stream,
                       x, pos, W1, b1, vb, qb);
    hipLaunchKernelGGL(agg_kernel, dim3(NBKT), dim3(256), 0, stream,
                       vb, qb, W2, b2, gcnt, coarse, out);
}

// Round 6
// 194.064 us; speedup vs baseline: 1.6611x; 1.1484x over previous
//
#include <hip/hip_runtime.h>
#include <math.h>

#define N_NODES 100000
#define N_EDGES 1600000
#define D_FEAT 32
#define D_HID 64
#define D_OUT 64
#define CAP 48          // per-node slot capacity; deg ~ Poisson(16), safe
#define NPB 64          // nodes per coarse bucket (1<<6)
#define NBKT 1563       // ceil(100000/64)
#define B1 256          // sort blocks; each owns a dense 6250-entry segment
#define E_PER_B1 6250   // 256 * 6250 = 1.6M edges exactly
#define NB_NODE 1024    // node-precompute blocks

typedef _Float16 half8 __attribute__((ext_vector_type(8)));
typedef float f32x4  __attribute__((ext_vector_type(4)));

// packed f16 relu(v + (-q)) on a channel pair, guaranteed lowering:
// exactly one v_pk_add_f16 + one v_pk_max_f16 (R2/R4 lesson: builtin
// elementwise ops on f16 vectors have uncertain codegen; asm does not).
__device__ inline unsigned pk_subrelu(unsigned v, unsigned nq) {
    unsigned r;
    asm("v_pk_add_f16 %0, %1, %2\n\t"
        "v_pk_max_f16 %0, %0, 0"
        : "=v"(r) : "v"(v), "v"(nq));
    return r;
}

// ---------------------------------------------------------------------------
// Kernel 1: per-node precompute (f32 math, f16 store, q stored NEGATED).
//   q[n][k] = pos[n] @ W1[32:35];  v[n][k] = b1[k] + x[n] @ W1[:32] + q[n][k]
// per-edge layer-1 output = relu(v[src] + nq[dst]).
// ---------------------------------------------------------------------------
__global__ __launch_bounds__(256)
void node_kernel(const float* __restrict__ x,
                 const float* __restrict__ pos,
                 const float* __restrict__ W1,
                 const float* __restrict__ b1,
                 unsigned short* __restrict__ vb,
                 unsigned short* __restrict__ qb) {
    const int lane = threadIdx.x & 63;
    const int wid  = (blockIdx.x * blockDim.x + threadIdx.x) >> 6;
    const int nw   = (NB_NODE * 256) >> 6;

    float w[D_FEAT + 3];
#pragma unroll
    for (int f = 0; f < D_FEAT + 3; ++f)
        w[f] = W1[f * D_HID + lane];
    const float bb = b1[lane];

    for (int node = wid; node < N_NODES; node += nw) {
        const float* xr = x + (size_t)node * D_FEAT;
        float acc = bb;
#pragma unroll
        for (int f = 0; f < D_FEAT; ++f)
            acc = fmaf(xr[f], w[f], acc);

        const float* pr = pos + (size_t)node * 3;
        float qa = 0.0f;
#pragma unroll
        for (int p = 0; p < 3; ++p)
            qa = fmaf(pr[p], w[D_FEAT + p], qa);

        vb[(size_t)node * D_HID + lane] =
            __builtin_bit_cast(unsigned short, (_Float16)(acc + qa));
        qb[(size_t)node * D_HID + lane] =
            __builtin_bit_cast(unsigned short, (_Float16)(-qa));
    }
}

// ---------------------------------------------------------------------------
// Kernel 2: dense local counting sort (replaces the atomic binning).
// R5 lesson: bin's 85us was NOT the reserve atomics (padding them was
// neutral) — it was 1.6M scattered 4B global appends (partial-line RFO +
// partial-sector writeback; WRITE_SIZE 90MB vs 32MB expected in R2).
// Each block sorts its 6250 edges by coarse bucket entirely in LDS
// (histogram -> 3-phase exclusive scan -> cursor placement into LDS stage),
// then writes ONE dense contiguous segment coarse[blk*6250..) (full lines)
// plus a per-block absolute bucket-start directory dir[blk][b].
// Zero global atomics, zero scattered global stores, no memset needed.
// Entry packing: (src << 6) | (dst & 63).
// ---------------------------------------------------------------------------
__global__ __launch_bounds__(1024)
void sort_kernel(const int* __restrict__ src,
                 const int* __restrict__ dst,
                 unsigned int* __restrict__ coarse,
                 int* __restrict__ dir) {
    __shared__ int hist[NBKT];       // counts -> starts -> cursors
    __shared__ int stage[E_PER_B1];  // 25 KB
    __shared__ int wsum[16];

    const int tid  = threadIdx.x;
    const int lane = tid & 63;
    const int wv   = tid >> 6;       // 0..15
    const int e0   = blockIdx.x * E_PER_B1;

    for (int b = tid; b < NBKT; b += 1024) hist[b] = 0;
    __syncthreads();

    for (int e = e0 + tid; e < e0 + E_PER_B1; e += 1024)
        atomicAdd(&hist[dst[e] >> 6], 1);
    __syncthreads();

    // ---- exclusive scan of hist (1563) in place: 2 elems/thread ----
    const int i0 = tid * 2;
    int c0 = (i0     < NBKT) ? hist[i0]     : 0;
    int c1 = (i0 + 1 < NBKT) ? hist[i0 + 1] : 0;
    const int sum = c0 + c1;
    int inc = sum;                       // wave-inclusive scan of chunk sums
#pragma unroll
    for (int d = 1; d < 64; d <<= 1) {
        int u = __shfl_up(inc, d, 64);
        if (lane >= d) inc += u;
    }
    if (lane == 63) wsum[wv] = inc;      // wave totals
    __syncthreads();
    if (wv == 0) {
        int s = (lane < 16) ? wsum[lane] : 0;
#pragma unroll
        for (int d = 1; d < 16; d <<= 1) {
            int u = __shfl_up(s, d, 64);
            if (lane >= d) s += u;
        }
        if (lane < 16) wsum[lane] = s;   // inclusive wave prefix
    }
    __syncthreads();
    const int excl = inc - sum + ((wv > 0) ? wsum[wv - 1] : 0);
    if (i0     < NBKT) hist[i0]     = excl;        // own slots only: no race
    if (i0 + 1 < NBKT) hist[i0 + 1] = excl + c0;
    __syncthreads();

    // ---- directory: absolute start of each bucket in this block's segment
    for (int b = tid; b < NBKT; b += 1024)
        dir[(size_t)blockIdx.x * NBKT + b] = e0 + hist[b];
    __syncthreads();                     // dir reads done before cursors move

    // ---- placement via LDS cursors into LDS staging ----
    for (int e = e0 + tid; e < e0 + E_PER_B1; e += 1024) {
        int d = dst[e], s = src[e];
        int p = atomicAdd(&hist[d >> 6], 1);   // p in [0, 6250) by construction
        stage[p] = (int)(((unsigned)s << 6) | (unsigned)(d & 63));
    }
    __syncthreads();

    // ---- dense, full-line copy-out ----
    for (int i = tid; i < E_PER_B1; i += 1024)
        coarse[e0 + i] = (unsigned)stage[i];
}

// ---------------------------------------------------------------------------
// Kernel 3: fused fine-bucketing + per-node MFMA aggregation.
// R0 structure preserved (256 thr = 4 waves, LDS slot lists, 16 nodes/wave);
// two deltas: (a) bucket edges gathered via the 256-segment directory
// (thread t walks block-t's contiguous segment); (b) afrag built with
// packed-f16 asm: 16 VALU/batch vs 56 for the bf16 unpack/sub/max/repack.
// Layer-2 via 4x2 mfma_f32_16x16x32_f16, register max, coalesced store.
// Padding rows use src = i (self-loop, idempotent under max).
// ---------------------------------------------------------------------------
__global__ __launch_bounds__(256)
void agg_kernel(const unsigned short* __restrict__ vb,
                const unsigned short* __restrict__ qb,
                const float* __restrict__ W2,
                const float* __restrict__ b2,
                const int* __restrict__ dir,
                const unsigned int* __restrict__ coarse,
                float* __restrict__ out) {
    __shared__ int lcnt[NPB];
    __shared__ int lslots[NPB][CAP];

    const int tid  = threadIdx.x;
    const int lane = tid & 63;
    const int wave = tid >> 6;             // 0..3
    const int quad = lane >> 4;
    const int mrow = lane & 15;
    const int bkt  = blockIdx.x;
    const int nbase = bkt << 6;

    // B fragments: bfrag[t][kh][j] = W2[kh*32 + quad*8 + j][t*16 + mrow] (f16)
    half8 bfrag[4][2];
#pragma unroll
    for (int t = 0; t < 4; ++t)
#pragma unroll
        for (int kh = 0; kh < 2; ++kh) {
            half8 f;
#pragma unroll
            for (int j = 0; j < 8; ++j)
                f[j] = (_Float16)W2[(kh * 32 + quad * 8 + j) * D_OUT + t * 16 + mrow];
            bfrag[t][kh] = f;
        }
    float bias[4];
#pragma unroll
    for (int t = 0; t < 4; ++t) bias[t] = b2[t * 16 + mrow];

    // fine bucketing into LDS: thread t gathers sort-block t's segment
    for (int i = tid; i < NPB; i += 256) lcnt[i] = 0;
    __syncthreads();
    {
        const int s0 = dir[(size_t)tid * NBKT + bkt];
        const int s1 = (bkt + 1 < NBKT) ? dir[(size_t)tid * NBKT + bkt + 1]
                                        : (tid + 1) * E_PER_B1;
        for (int j = s0; j < s1; ++j) {
            unsigned enc = coarse[j];
            int local = (int)(enc & 63u);
            int s     = (int)(enc >> 6);
            int p = atomicAdd(&lcnt[local], 1);
            if (p < CAP) lslots[local][p] = s;
        }
    }
    __syncthreads();

    // per-node aggregation, 16 nodes per wave
    for (int ln = wave; ln < NPB; ln += 4) {
        const int node = nbase + ln;
        if (node >= N_NODES) break;

        const uint4 nq0 = *(const uint4*)(qb + (size_t)node * D_HID + quad * 8);
        const uint4 nq1 = *(const uint4*)(qb + (size_t)node * D_HID + 32 + quad * 8);

        int deg = lcnt[ln];
        if (deg > CAP) deg = CAP;
        const int rows = deg + 1;              // + self-loop
        const int nbat = (rows + 15) >> 4;

        float rmax[4][4];
#pragma unroll
        for (int t = 0; t < 4; ++t)
#pragma unroll
            for (int r = 0; r < 4; ++r) rmax[t][r] = -INFINITY;

        for (int b = 0; b < nbat; ++b) {
            int idx = b * 16 + mrow;
            int idxc = (idx < CAP) ? idx : (CAP - 1);    // clamp LDS read
            int s = (idx < deg) ? lslots[ln][idxc] : node;

            const uint4 v0 = *(const uint4*)(vb + (size_t)s * D_HID + quad * 8);
            const uint4 v1 = *(const uint4*)(vb + (size_t)s * D_HID + 32 + quad * 8);

            uint4 a0u, a1u;
            a0u.x = pk_subrelu(v0.x, nq0.x);
            a0u.y = pk_subrelu(v0.y, nq0.y);
            a0u.z = pk_subrelu(v0.z, nq0.z);
            a0u.w = pk_subrelu(v0.w, nq0.w);
            a1u.x = pk_subrelu(v1.x, nq1.x);
            a1u.y = pk_subrelu(v1.y, nq1.y);
            a1u.z = pk_subrelu(v1.z, nq1.z);
            a1u.w = pk_subrelu(v1.w, nq1.w);
            half8 a0 = __builtin_bit_cast(half8, a0u);
            half8 a1 = __builtin_bit_cast(half8, a1u);

#pragma unroll
            for (int t = 0; t < 4; ++t) {
                f32x4 acc = (f32x4){0.f, 0.f, 0.f, 0.f};
                acc = __builtin_amdgcn_mfma_f32_16x16x32_f16(a0, bfrag[t][0], acc, 0, 0, 0);
                acc = __builtin_amdgcn_mfma_f32_16x16x32_f16(a1, bfrag[t][1], acc, 0, 0, 0);
#pragma unroll
                for (int r = 0; r < 4; ++r)
                    rmax[t][r] = fmaxf(rmax[t][r], acc[r]);
            }
        }

        float fin[4];
#pragma unroll
        for (int t = 0; t < 4; ++t) {
            float m = fmaxf(fmaxf(rmax[t][0], rmax[t][1]), fmaxf(rmax[t][2], rmax[t][3]));
            m = fmaxf(m, __shfl_xor(m, 16, 64));
            m = fmaxf(m, __shfl_xor(m, 32, 64));
            fin[t] = m + bias[t];
        }
        float r = (quad == 0) ? fin[0] : (quad == 1) ? fin[1] : (quad == 2) ? fin[2] : fin[3];
        out[(size_t)node * D_OUT + lane] = r;
    }
}

// ---------------------------------------------------------------------------
extern "C" void kernel_launch(void* const* d_in, const int* in_sizes, int n_in,
                              void* d_out, int out_size, void* d_ws, size_t ws_size,
                              hipStream_t stream) {
    const float* x   = (const float*)d_in[0];
    const float* pos = (const float*)d_in[1];
    const int*   ei  = (const int*)d_in[2];   // [2][N_EDGES]: row0=src, row1=dst
    const float* W1  = (const float*)d_in[3];
    const float* b1  = (const float*)d_in[4];
    const float* W2  = (const float*)d_in[5];
    const float* b2  = (const float*)d_in[6];
    float* out = (float*)d_out;

    char* ws = (char*)d_ws;
    unsigned short* vb   = (unsigned short*)ws;                     // 12.8 MB (f16 v)
    unsigned short* qb   = (unsigned short*)(ws + 12800000);        // 12.8 MB (f16 -q)
    unsigned int* coarse = (unsigned int*)(ws + 25600000);          // 6.4 MB
    int*            dir  = (int*)(ws + 32000000);                   // 1.6 MB

    const int* src = ei;
    const int* dst = ei + N_EDGES;

    hipLaunchKernelGGL(sort_kernel, dim3(B1), dim3(1024), 0, stream,
                       src, dst, coarse, dir);
    hipLaunchKernelGGL(node_kernel, dim3(NB_NODE), dim3(256), 0, stream,
                       x, pos, W1, b1, vb, qb);
    hipLaunchKernelGGL(agg_kernel, dim3(NBKT), dim3(256), 0, stream,
                       vb, qb, W2, b2, dir, coarse, out);
}